// Round 3
// baseline (6043.615 us; speedup 1.0000x reference)
//
#include <hip/hip_runtime.h>
#include <hip/hip_bf16.h>
#include <math.h>
#include <stdio.h>

typedef unsigned short u16;
typedef unsigned int u32;
typedef __attribute__((ext_vector_type(8))) short short8;   // bf16x8 fragment (4 VGPRs)
typedef __attribute__((ext_vector_type(4))) float float4v;  // fp32x4 accumulator
typedef __attribute__((ext_vector_type(4))) u32  uint4v;    // 16B vector copy
typedef __attribute__((ext_vector_type(2))) u32  uint2v;    // 8B vector copy

static __device__ __forceinline__ float bf2f(u16 u) {
    return __uint_as_float(((u32)u) << 16);
}
static __device__ __forceinline__ u16 f2bf(float f) {
    u32 x = __float_as_uint(f);
    x += 0x7FFFu + ((x >> 16) & 1u);   // RNE
    return (u16)(x >> 16);
}
static __device__ __forceinline__ float gelu_exact(float x) {
    return 0.5f * x * (1.0f + erff(x * 0.70710678118654752f));
}

// ---------------------------------------------------------------------------
// Input-dtype probe: decides whether d_in tensors are bf16 (flag=1) or fp32
// (flag=0). For bf16 data, the LOW u16 of each u32 word is a bf16 of N(0,1)
// whose exponent field lies in [108,134] essentially always; for fp32 data
// those bits are random mantissa (~10% hit rate). Majority vote over 256 words.
// ---------------------------------------------------------------------------
__global__ void detect_k(const u32* __restrict__ x, u32* __restrict__ flag) {
    __shared__ int cnt;
    if (threadIdx.x == 0) cnt = 0;
    __syncthreads();
    u32 w = x[threadIdx.x];
    int e = (w >> 7) & 0xFF;
    if (e >= 108 && e <= 134) atomicAdd(&cnt, 1);
    __syncthreads();
    if (threadIdx.x == 0) *flag = (cnt > 128) ? 1u : 0u;
}

// Canonicalize one input tensor to bf16 (copy if already bf16, RNE-cast if fp32)
__global__ void convert_k(const void* __restrict__ src, u16* __restrict__ dst,
                          long n, const u32* __restrict__ flag) {
    long i = (long)blockIdx.x * 256 + threadIdx.x;
    if (i >= n) return;
    if (*flag) dst[i] = ((const u16*)src)[i];
    else       dst[i] = f2bf(((const float*)src)[i]);
}

// ---------------------------------------------------------------------------
// Generic bf16 MFMA GEMM: C = A[M,K] * B + bias, epilogue variants.
//   layb=0: B is [K,N] row-major (ldB = row stride)
//   layb=1: B is [N,K] row-major (B^T logical, used for Q*K^T)
// epi: 0 f32+bias | 1 bf16+bias+gelu | 2 f32+bias+gelu | 3 qkv-scatter
//      4 f32 no bias | 5 bf16 no bias
// ---------------------------------------------------------------------------
struct GemmParams {
    const u16* A; const u16* B; const u16* bias;
    float* Cf; u16* Cb;
    int M, N, K;
    int ldA, ldB, ldC;
    long sA, sB, sC;       // batch strides (elements), batch = blockIdx.z
    int layb;
    int epi;
    // qkv scatter extras:
    u16 *q, *k, *v;
    int Tpad, Dh;
};

#define BM 64
#define BN 64
#define BK 32
#define LDSS 40  // padded K-stride in LDS (rows at 80B: 16B-aligned, 2-way bank alias max = free)

__global__ __launch_bounds__(256) void gemm_k(GemmParams p) {
    __shared__ __align__(16) u16 As[BM][LDSS];
    __shared__ __align__(16) u16 Bs[BN][LDSS];   // stored transposed: Bs[n][k]

    const int tid  = threadIdx.x;
    const int bz   = blockIdx.z;
    const int bn0  = blockIdx.x * BN;
    const int bm0  = blockIdx.y * BM;
    const u16* A = p.A + (long)bz * p.sA;
    const u16* B = p.B + (long)bz * p.sB;

    const int lane = tid & 63;
    const int wave = tid >> 6;
    const int wm   = (wave >> 1) * 32;
    const int wn   = (wave & 1) * 32;
    const int lrow = lane & 15;
    const int quad = lane >> 4;

    float4v acc[2][2] = {};

    // A staging: 64 rows x 32 cols, 16B per thread
    const int a_row = tid >> 2;
    const int a_col = (tid & 3) << 3;
    int ga_row = bm0 + a_row; if (ga_row >= p.M) ga_row = p.M - 1;

    for (int k0 = 0; k0 < p.K; k0 += BK) {
        // ---- stage A tile ----
        {
            const uint4v* src = (const uint4v*)(A + (long)ga_row * p.ldA + k0 + a_col);
            *(uint4v*)&As[a_row][a_col] = *src;
        }
        // ---- stage B tile (transposed into LDS) ----
        if (p.layb == 1) {
            int n  = tid >> 2;
            int kg = (tid & 3) << 3;
            int gn = bn0 + n; if (gn >= p.N) gn = p.N - 1;
            const uint4v* src = (const uint4v*)(B + (long)gn * p.ldB + k0 + kg);
            *(uint4v*)&Bs[n][kg] = *src;
        } else {
            int kk = tid >> 3;            // 0..31
            int ng = (tid & 7) << 3;      // 0..56
            union { uint4v v; u16 e[8]; } tmp;   // union pun: defined behavior
            tmp.v = *(const uint4v*)(B + (long)(k0 + kk) * p.ldB + bn0 + ng);
            #pragma unroll
            for (int j = 0; j < 8; ++j) Bs[ng + j][kk] = tmp.e[j];
        }
        __syncthreads();

        short8 af[2], bfr[2];
        #pragma unroll
        for (int mi = 0; mi < 2; ++mi)
            af[mi] = *(const short8*)&As[wm + mi * 16 + lrow][quad * 8];
        #pragma unroll
        for (int ni = 0; ni < 2; ++ni)
            bfr[ni] = *(const short8*)&Bs[wn + ni * 16 + lrow][quad * 8];
        #pragma unroll
        for (int mi = 0; mi < 2; ++mi)
            #pragma unroll
            for (int ni = 0; ni < 2; ++ni)
                acc[mi][ni] = __builtin_amdgcn_mfma_f32_16x16x32_bf16(
                    af[mi], bfr[ni], acc[mi][ni], 0, 0, 0);
        __syncthreads();
    }

    // ---- epilogue ----  C/D layout: col = lane&15, row = quad*4 + r  (verified m89)
    #pragma unroll
    for (int mi = 0; mi < 2; ++mi) {
        #pragma unroll
        for (int ni = 0; ni < 2; ++ni) {
            #pragma unroll
            for (int r = 0; r < 4; ++r) {
                int row = bm0 + wm + mi * 16 + quad * 4 + r;
                int col = bn0 + wn + ni * 16 + lrow;
                if (row >= p.M || col >= p.N) continue;
                float val = acc[mi][ni][r];
                if (p.epi == 3) {
                    val += bf2f(p.bias[col]);
                    int head = col / 768;
                    int rem  = col - head * 768;
                    int f    = rem / 3;
                    int c    = rem - f * 3;
                    if (c < 2) val *= 0.0625f;       // 1/sqrt(256)
                    u16* dst = (c == 0 ? p.q : (c == 1 ? p.k : p.v));
                    dst[(long)head * p.Tpad * p.Dh + (long)row * p.Dh + f] = f2bf(val);
                } else {
                    if (p.epi <= 2) val += bf2f(p.bias[col]);
                    if (p.epi == 1 || p.epi == 2) val = gelu_exact(val);
                    long off = (long)bz * p.sC + (long)row * p.ldC + col;
                    if (p.epi == 0 || p.epi == 2 || p.epi == 4) p.Cf[off] = val;
                    else p.Cb[off] = f2bf(val);
                }
            }
        }
    }
}

// ---------------------------------------------------------------------------
// LayerNorm: one wave per row of 256, fp32 in -> bf16 out (scaled by g,b)
// ---------------------------------------------------------------------------
__global__ __launch_bounds__(256) void ln_k(const float* __restrict__ h,
                                            const u16* __restrict__ g,
                                            const u16* __restrict__ b,
                                            u16* __restrict__ out, int M) {
    int row  = blockIdx.x * 4 + (threadIdx.x >> 6);
    int lane = threadIdx.x & 63;
    if (row >= M) return;
    const float* x = h + (long)row * 256;
    float4v v = *(const float4v*)(x + lane * 4);
    float s  = v[0] + v[1] + v[2] + v[3];
    float s2 = v[0] * v[0] + v[1] * v[1] + v[2] * v[2] + v[3] * v[3];
    #pragma unroll
    for (int off = 32; off; off >>= 1) {
        s  += __shfl_xor(s, off, 64);
        s2 += __shfl_xor(s2, off, 64);
    }
    float mean = s * (1.0f / 256.0f);
    float var  = s2 * (1.0f / 256.0f) - mean * mean;
    float rs   = rsqrtf(var + 1e-5f);
    union { uint2v v; u16 e[4]; } o;
    #pragma unroll
    for (int j = 0; j < 4; ++j) {
        int c = lane * 4 + j;
        o.e[j] = f2bf((v[j] - mean) * rs * bf2f(g[c]) + bf2f(b[c]));
    }
    *(uint2v*)&out[(long)row * 256 + lane * 4] = o.v;
}

// ---------------------------------------------------------------------------
// Softmax over rows of length 1026 (ld 1056), fp32 in -> bf16 out, zero pad.
// One wave per row. rows = 8 heads * 1026.
// ---------------------------------------------------------------------------
__global__ __launch_bounds__(256) void softmax_k(const float* __restrict__ S,
                                                 u16* __restrict__ P, int rows) {
    int row  = blockIdx.x * 4 + (threadIdx.x >> 6);
    int lane = threadIdx.x & 63;
    if (row >= rows) return;
    int z = row / 1026, t = row - z * 1026;
    const float* src = S + (long)z * (1026L * 1056) + (long)t * 1056;
    u16* dst         = P + (long)z * (1026L * 1056) + (long)t * 1056;
    float vals[17];
    float m = -1e30f;
    #pragma unroll
    for (int i = 0; i < 17; ++i) {
        int idx = lane + i * 64;
        vals[i] = (idx < 1026) ? src[idx] : -1e30f;
        m = fmaxf(m, vals[i]);
    }
    #pragma unroll
    for (int off = 32; off; off >>= 1) m = fmaxf(m, __shfl_xor(m, off, 64));
    float sum = 0.0f;
    #pragma unroll
    for (int i = 0; i < 17; ++i) {
        int idx = lane + i * 64;
        if (idx < 1026) { vals[i] = __expf(vals[i] - m); sum += vals[i]; }
    }
    #pragma unroll
    for (int off = 32; off; off >>= 1) sum += __shfl_xor(sum, off, 64);
    float inv = 1.0f / sum;
    #pragma unroll
    for (int i = 0; i < 17; ++i) {
        int idx = lane + i * 64;
        if (idx < 1056) dst[idx] = f2bf(idx < 1026 ? vals[i] * inv : 0.0f);
    }
}

// ---------------------------------------------------------------------------
// Zero the pad rows (1026..1055) of q/k/v buffers so no stage reads poison.
// ---------------------------------------------------------------------------
__global__ void padzero_k(u16* __restrict__ qb, u16* __restrict__ kb,
                          u16* __restrict__ vb) {
    int i = blockIdx.x * 256 + threadIdx.x;      // 0 .. 61439
    int head = i / (30 * 256);
    int rem  = i - head * (30 * 256);
    int r    = rem >> 8;
    int c    = rem & 255;
    long off = (long)head * 1056 * 256 + (long)(1026 + r) * 256 + c;
    qb[off] = 0; kb[off] = 0; vb[off] = 0;
}

// ---------------------------------------------------------------------------
// Embed: h[b,t,:] = t<1024 ? x[b,t,:] : (t==1024 ? cls : dict), bf16 -> fp32
// ---------------------------------------------------------------------------
__global__ void embed_k(const u16* __restrict__ x, const u16* __restrict__ cls,
                        const u16* __restrict__ dict, float* __restrict__ h) {
    long i = (long)blockIdx.x * 256 + threadIdx.x;
    int d = i & 255;
    long row = i >> 8;
    int b = (int)(row / 1026), t = (int)(row - (long)b * 1026);
    u16 u;
    if (t < 1024) u = x[((long)b * 1024 + t) * 256 + d];
    else if (t == 1024) u = cls[d];
    else u = dict[d];
    h[i] = bf2f(u);
}

// ---------------------------------------------------------------------------
// Output: split h into (x-part, cls, dict) concat order; dtype follows flag.
// ---------------------------------------------------------------------------
__global__ void outconv_k(const float* __restrict__ h, void* __restrict__ out,
                          const u32* __restrict__ flag) {
    long i = (long)blockIdx.x * 256 + threadIdx.x;
    int d = i & 255;
    long row = i >> 8;
    int b = (int)(row / 1026), t = (int)(row - (long)b * 1026);
    long o;
    if (t < 1024)       o = ((long)b * 1024 + t) * 256 + d;
    else if (t == 1024) o = 8L * 1024 * 256 + (long)b * 256 + d;
    else                o = 8L * 1024 * 256 + 8L * 256 + (long)b * 256 + d;
    float v = h[i];
    if (*flag) ((u16*)out)[o] = f2bf(v);
    else       ((float*)out)[o] = v;
}

// ---------------------------------------------------------------------------
static void gemm_launch(hipStream_t stream, const GemmParams& p, int batches) {
    dim3 grid((p.N + BN - 1) / BN, (p.M + BM - 1) / BM, batches);
    hipLaunchKernelGGL(gemm_k, grid, dim3(256), 0, stream, p);
}

extern "C" void kernel_launch(void* const* d_in, const int* in_sizes, int n_in,
                              void* d_out, int out_size, void* d_ws, size_t ws_size,
                              hipStream_t stream) {
    const int Mrows = 8 * 1026;     // 8208
    char* ws = (char*)d_ws;
    size_t used = 0;
    auto alloc = [&](size_t bytes) {
        char* ptr = ws + used;
        used += (bytes + 255) & ~(size_t)255;
        return ptr;
    };
    u32*   flag = (u32*)  alloc(256);
    float* h    = (float*)alloc((size_t)Mrows * 256 * 4);
    u16*   hn   = (u16*)  alloc((size_t)Mrows * 256 * 2);
    u16*   qb   = (u16*)  alloc(8L * 1056 * 256 * 2);
    u16*   kb   = (u16*)  alloc(8L * 1056 * 256 * 2);
    u16*   vb   = (u16*)  alloc(8L * 1056 * 256 * 2);
    float* S    = (float*)alloc(8L * 1026 * 1056 * 4);
    u16*   P    = (u16*)  alloc(8L * 1026 * 1056 * 2);
    u16*   ao   = (u16*)  alloc((size_t)Mrows * 2048 * 2);
    u16*   mid  = (u16*)  alloc((size_t)Mrows * 1024 * 2);

    // canonical bf16 copies of all inputs (dtype-adaptive)
    u16* canon[15];
    size_t canon_bytes = 0;
    for (int i = 0; i < 15 && i < n_in; ++i) canon_bytes += ((size_t)in_sizes[i] * 2 + 255) & ~(size_t)255;
    bool do_convert = (used + canon_bytes <= ws_size);
    if (do_convert) {
        for (int i = 0; i < 15 && i < n_in; ++i) canon[i] = (u16*)alloc((size_t)in_sizes[i] * 2);
    } else {
        for (int i = 0; i < 15 && i < n_in; ++i) canon[i] = (u16*)d_in[i];  // assume bf16
        fprintf(stderr, "kernel_launch: ws too small for canon (%zu + %zu > %zu)\n",
                used, canon_bytes, ws_size);
    }
    if (used > ws_size) {
        fprintf(stderr, "kernel_launch: need %zu ws bytes, have %zu\n", used, ws_size);
        return;
    }

    detect_k<<<1, 256, 0, stream>>>((const u32*)d_in[0], flag);
    if (do_convert) {
        for (int i = 0; i < 15 && i < n_in; ++i) {
            long n = in_sizes[i];
            convert_k<<<(int)((n + 255) / 256), 256, 0, stream>>>(d_in[i], canon[i], n, flag);
        }
    }

    const u16* x      = canon[0];
    const u16* cls    = canon[1];
    const u16* dict   = canon[2];
    const u16* ln1_g  = canon[3];
    const u16* ln1_b  = canon[4];
    const u16* qkv_w  = canon[5];
    const u16* qkv_b  = canon[6];
    const u16* proj_w = canon[7];
    const u16* proj_b = canon[8];
    const u16* ln2_g  = canon[9];
    const u16* ln2_b  = canon[10];
    const u16* mlp_w1 = canon[11];
    const u16* mlp_b1 = canon[12];
    const u16* mlp_w2 = canon[13];
    const u16* mlp_b2 = canon[14];

    embed_k<<<Mrows, 256, 0, stream>>>(x, cls, dict, h);
    padzero_k<<<240, 256, 0, stream>>>(qb, kb, vb);

    for (int l = 0; l < 6; ++l) {
        ln_k<<<(Mrows + 3) / 4, 256, 0, stream>>>(h, ln1_g + l * 256, ln1_b + l * 256, hn, Mrows);

        for (int b = 0; b < 8; ++b) {
            {   // qkv projection for batch b, scatter into q/k/v [H,1056,256]
                GemmParams p{};
                p.A = hn + (long)b * 1026 * 256; p.ldA = 256;
                p.B = qkv_w + (long)l * 256 * 6144; p.ldB = 6144; p.layb = 0;
                p.bias = qkv_b + (long)l * 6144;
                p.M = 1026; p.N = 6144; p.K = 256;
                p.epi = 3; p.q = qb; p.k = kb; p.v = vb; p.Tpad = 1056; p.Dh = 256;
                gemm_launch(stream, p, 1);
            }
            {   // S = Q K^T, batched over 8 heads
                GemmParams p{};
                p.A = qb; p.ldA = 256; p.sA = 1056L * 256;
                p.B = kb; p.ldB = 256; p.sB = 1056L * 256; p.layb = 1;
                p.M = 1026; p.N = 1026; p.K = 256;
                p.Cf = S; p.ldC = 1056; p.sC = 1026L * 1056;
                p.epi = 4;
                gemm_launch(stream, p, 8);
            }
            softmax_k<<<(8 * 1026 + 3) / 4, 256, 0, stream>>>(S, P, 8 * 1026);
            {   // O = P V, scatter into attn_out [t, h*256+d]
                GemmParams p{};
                p.A = (const u16*)P; p.ldA = 1056; p.sA = 1026L * 1056;
                p.B = vb; p.ldB = 256; p.sB = 1056L * 256; p.layb = 0;
                p.M = 1026; p.N = 256; p.K = 1056;
                p.Cb = ao + (long)b * 1026 * 2048; p.ldC = 2048; p.sC = 256;
                p.epi = 5;
                gemm_launch(stream, p, 8);
            }
        }
        {   // proj: h = attn_out @ proj_w + proj_b (fp32)
            GemmParams p{};
            p.A = ao; p.ldA = 2048;
            p.B = proj_w + (long)l * 2048 * 256; p.ldB = 256; p.layb = 0;
            p.bias = proj_b + (long)l * 256;
            p.M = Mrows; p.N = 256; p.K = 2048;
            p.Cf = h; p.ldC = 256; p.epi = 0;
            gemm_launch(stream, p, 1);
        }
        ln_k<<<(Mrows + 3) / 4, 256, 0, stream>>>(h, ln2_g + l * 256, ln2_b + l * 256, hn, Mrows);
        {   // mlp1: mid = gelu(hn @ w1 + b1) (bf16)
            GemmParams p{};
            p.A = hn; p.ldA = 256;
            p.B = mlp_w1 + (long)l * 256 * 1024; p.ldB = 1024; p.layb = 0;
            p.bias = mlp_b1 + (long)l * 1024;
            p.M = Mrows; p.N = 1024; p.K = 256;
            p.Cb = mid; p.ldC = 1024; p.epi = 1;
            gemm_launch(stream, p, 1);
        }
        {   // mlp2: h = gelu(mid @ w2 + b2) (fp32, next layer input)
            GemmParams p{};
            p.A = mid; p.ldA = 1024;
            p.B = mlp_w2 + (long)l * 1024 * 256; p.ldB = 256; p.layb = 0;
            p.bias = mlp_b2 + (long)l * 256;
            p.M = Mrows; p.N = 256; p.K = 1024;
            p.Cf = h; p.ldC = 256; p.epi = 2;
            gemm_launch(stream, p, 1);
        }
    }

    outconv_k<<<Mrows, 256, 0, stream>>>(h, d_out, flag);
}